// Round 11
// baseline (3957.603 us; speedup 1.0000x reference)
//
#include <hip/hip_runtime.h>
#include <hip/hip_bf16.h>
#include <math.h>

#define BATCH 16
#define HID   128
#define NX    128
#define NF    4
#define NT    64
#define MODES 96
#define NWG   256
#define TPB   1024
#define NGRP  8             // groups (2 batches each)
#define GSZ   32            // WGs per group
#define ZSZ   ((size_t)BATCH * NX * HID)   // zbuf slice: [b][x][h]

// ---------------------------------------------------------------------------
// Tables: k_m=(80+m)%128. Ct/St scalar m-major; T2m[m][x]={c,s}.
// ---------------------------------------------------------------------------
__global__ void k_tables(float* __restrict__ C, float* __restrict__ S,
                         float2* __restrict__ T2m) {
    int m = blockIdx.x, x = threadIdx.x;
    if (x < NX) {
        int k = (80 + m) % NX;
        float ang = (float)((k * x) & (NX - 1)) * (2.0f * (float)M_PI / (float)NX);
        float c = cosf(ang), s = sinf(ang);
        C[m * NX + x] = c;
        S[m * NX + x] = s;
        T2m[m * NX + x] = make_float2(c, s);
    }
}

// ---------------------------------------------------------------------------
// dxi[t][b][x][n] = xi[b,n,x,t+1] - xi[b,n,x,t]
// ---------------------------------------------------------------------------
__global__ void k_dxi(const float* __restrict__ xi, float* __restrict__ dxi) {
    int idx = blockIdx.x * blockDim.x + threadIdx.x;
    const int total = (NT - 1) * BATCH * NX * NF;
    if (idx < total) {
        int n = idx & (NF - 1);
        int x = (idx >> 2) & (NX - 1);
        int b = (idx >> 9) & (BATCH - 1);
        int t = idx >> 13;
        const float* base = xi + (((size_t)b * NF + n) * NX + x) * NT;
        dxi[idx] = base[t + 1] - base[t];
    }
}

// ---------------------------------------------------------------------------
// Wt4[j][h][ol] = {WF[o][h], WG[o][0..2][h]}, Wt1[j][h][ol] = WG[o][3][h],
// o = j*8+ol.
// ---------------------------------------------------------------------------
__global__ void k_wt4(const float* __restrict__ WF, const float* __restrict__ WGm,
                      float4* __restrict__ Wt4, float* __restrict__ Wt1) {
    int idx = blockIdx.x * 256 + threadIdx.x;
    if (idx < 16 * HID * 8) {
        int ol = idx & 7, h = (idx >> 3) & 127, j = idx >> 10;
        int o = j * 8 + ol;
        Wt4[idx] = make_float4(WF[(size_t)o * HID + h],
                               WGm[((size_t)o * NF + 0) * HID + h],
                               WGm[((size_t)o * NF + 1) * HID + h],
                               WGm[((size_t)o * NF + 2) * HID + h]);
        Wt1[idx] = WGm[((size_t)o * NF + 3) * HID + h];
    }
}

// ---------------------------------------------------------------------------
// At2b[m][h][o] = pack_bf16(A[0][m][o][h], A[1][m][o][h])  (4 B/entry)
// ---------------------------------------------------------------------------
__global__ void k_at2(const float* __restrict__ A, unsigned int* __restrict__ At2b) {
    __shared__ float t0[32][33], t1[32][33];
    int m = blockIdx.z;
    int h0 = blockIdx.x * 32, o0 = blockIdx.y * 32;
    int tx = threadIdx.x, ty = threadIdx.y;
    const float* A0 = A + (size_t)m * HID * HID;
    const float* A1 = A0 + (size_t)MODES * HID * HID;
    #pragma unroll
    for (int j = 0; j < 32; j += 8) {
        t0[ty + j][tx] = A0[(size_t)(o0 + ty + j) * HID + h0 + tx];
        t1[ty + j][tx] = A1[(size_t)(o0 + ty + j) * HID + h0 + tx];
    }
    __syncthreads();
    #pragma unroll
    for (int j = 0; j < 32; j += 8) {
        __hip_bfloat16 b0 = __float2bfloat16(t0[tx][ty + j]);
        __hip_bfloat16 b1 = __float2bfloat16(t1[tx][ty + j]);
        unsigned int u = (unsigned int)(*(unsigned short*)&b0)
                       | ((unsigned int)(*(unsigned short*)&b1) << 16);
        At2b[((size_t)m * HID + h0 + ty + j) * HID + o0 + tx] = u;
    }
}

// ---------------------------------------------------------------------------
// Persistent solver: 8 groups x 32 WGs x 1024 thr, group = w&7 (XCD-compact
// under round-robin dispatch; correctness does not depend on placement).
// Group g owns batches 2g, 2g+1.  j = w>>3 (0..31):
//   P1  : jb=j&1, x-tile=(j>>1)*8   IDFT -> zbuf
//   P2a : jb=j&1, o-tile=(j>>1)*8   W-GEMM+tanh+dxi -> Hc
//   P2b : m-tile=j*3; threads (o128, m3, b2)  DFT+Av(bf16)+update
// ---------------------------------------------------------------------------
__global__ __launch_bounds__(TPB, 1) void k_solve(
    const float* __restrict__ z0, const float* __restrict__ Ct,
    const float* __restrict__ St, const float2* __restrict__ T2m,
    const float4* __restrict__ Wt4g, const float* __restrict__ Wt1g,
    const unsigned int* __restrict__ At2b, const float* __restrict__ dxi,
    float2* __restrict__ va, float2* __restrict__ vb,
    float* __restrict__ zbuf, float* __restrict__ Hc,
    float* __restrict__ out, int* __restrict__ barc)
{
    __shared__ float2 CS[MODES][8];     // P1 trig (persistent)        6 KB
    __shared__ float  zsl[NX][132];     // P2a z tile [x][h]          67.6 KB
    __shared__ float4 Wsl4[HID][8];     // P2a W (persistent)         16 KB
    __shared__ float  Wsl1[HID][9];     //                             4.6 KB
    __shared__ float  dxs[NX][5];       // P2a dxi                     2.5 KB
    __shared__ float2 vsl[2][3][HID];   // P2b v slices (2 b x 3 m)    6 KB

    const int w = blockIdx.x;
    const int t = threadIdx.x;
    const int g = w & 7;                // group (XCD-compact heuristic)
    const int j = w >> 3;               // role 0..31
    const int jb = j & 1;
    const int j2 = j >> 1;              // 0..15
    const int bP = g * 2 + jb;          // P1/P2a/flush batch
    const int xg0 = j2 * 8;             // P1/flush x-tile
    const int o0 = j2 * 8;              // P2a o-tile
    const int m0v = j2 * 6;             // v0 m-tile
    const int m0 = j * 3;               // P2b m-tile

    int nbar = 0;
    int* ctr = barc + g * 64;
    auto gbar = [&]() {
        ++nbar;
        __syncthreads();
        if (t == 0) {
            __hip_atomic_fetch_add(ctr, 1, __ATOMIC_RELEASE,
                                   __HIP_MEMORY_SCOPE_AGENT);
            while (__hip_atomic_load(ctr, __ATOMIC_RELAXED,
                                     __HIP_MEMORY_SCOPE_AGENT) < GSZ * nbar)
                __builtin_amdgcn_s_sleep(2);
            (void)__hip_atomic_load(ctr, __ATOMIC_ACQUIRE,
                                    __HIP_MEMORY_SCOPE_AGENT);
        }
        __syncthreads();
    };

    // persistent P1 trig for x-tile
    if (t < MODES * 8) {
        int m = t >> 3, xp = t & 7;
        CS[m][xp] = T2m[m * NX + xg0 + xp];
    }
    // persistent W slice for o-tile
    {
        int h = t >> 3, ol = t & 7;
        Wsl4[h][ol] = Wt4g[((size_t)j2 * HID + h) * 8 + ol];
        Wsl1[h][ol] = Wt1g[((size_t)j2 * HID + h) * 8 + ol];
    }

    // ---- v0: (jb, j2) computes v0[bP][m-tile 6][h] ----
    {
        int h = t & 127, q = t >> 7;        // q 0..7
        int c = q & 1, mq = q >> 1;         // mq 0..3
        const float* zr = z0 + ((size_t)bP * HID + h) * NX;
        float* fva = (float*)va;
        #pragma unroll
        for (int jj = 0; jj < 2; ++jj) {
            int mm = mq + 4 * jj;
            if (mm < 6) {
                int m = m0v + mm;
                const float* Trow = (c ? St : Ct) + m * NX;
                float acc = 0.f;
                #pragma unroll 4
                for (int x = 0; x < NX; ++x) acc += zr[x] * Trow[x];
                if (c) acc = -acc;
                fva[(((size_t)bP * MODES + m) * HID + h) * 2 + c] = acc;
            }
        }
    }
    gbar();

    float2* vcur = va;
    float2* vnxt = vb;

    for (int step = 0; step < NT; ++step) {
        // ---- WG-local flush (reads only this WG's own prior writes) ----
        if (step > 0 && (step & 15) == 0) {
            int t0 = step - 16;
            int xl = t >> 7, h = t & 127;
            int x = xg0 + xl;
            float vals[16];
            #pragma unroll
            for (int tt = 0; tt < 16; ++tt)
                vals[tt] = zbuf[(size_t)tt * ZSZ + ((size_t)bP * NX + x) * HID + h];
            float* dst = out + (((size_t)bP * HID + h) * NX + x) * NT + t0;
            #pragma unroll
            for (int q = 0; q < 4; ++q)
                ((float4*)dst)[q] = make_float4(vals[q*4], vals[q*4+1],
                                                vals[q*4+2], vals[q*4+3]);
        }

        // ---- P1: IDFT -> zbuf[step&15][bP][x][h] ----
        {
            int h = t & 127, xp = t >> 7;   // xp 0..7
            const float2* vr = vcur + (size_t)bP * MODES * HID + h;
            float acc = 0.f;
            #pragma unroll 4
            for (int m = 0; m < MODES; ++m) {
                float2 vv = vr[(size_t)m * HID];
                float2 cs = CS[m][xp];
                acc += vv.x * cs.x - vv.y * cs.y;
            }
            acc *= 0.0078125f;
            zbuf[(size_t)(step & 15) * ZSZ + ((size_t)bP * NX + xg0 + xp) * HID + h] = acc;
        }
        if (step == NT - 1) break;
        gbar();

        // ---- P2a: W-GEMM + tanh + dxi -> Hc[bP][x][o-tile] ----
        {
            const float4* z4 = (const float4*)(zbuf + (size_t)(step & 15) * ZSZ
                                               + (size_t)bP * NX * HID);
            #pragma unroll
            for (int k = 0; k < 4; ++k) {
                int idx = t + k * 1024;
                int x = idx >> 5, h4 = (idx & 31) * 4;
                *(float4*)&zsl[x][h4] = z4[idx];
            }
            if (t < 512)
                dxs[t >> 2][t & 3] =
                    dxi[((size_t)step * BATCH + bP) * NX * NF + t];
            __syncthreads();

            int ol = t & 7, x = t >> 3;     // 8 o x 128 x
            float a0 = 0.f, a1 = 0.f, a2 = 0.f, a3 = 0.f, a4 = 0.f;
            #pragma unroll 4
            for (int h = 0; h < HID; ++h) {
                float zv = zsl[x][h];
                float4 w4 = Wsl4[h][ol];
                float w1 = Wsl1[h][ol];
                a0 += w4.x * zv; a1 += w4.y * zv;
                a2 += w4.z * zv; a3 += w4.w * zv;
                a4 += w1 * zv;
            }
            float hv = tanhf(a0)
                     + tanhf(a1) * dxs[x][0]
                     + tanhf(a2) * dxs[x][1]
                     + tanhf(a3) * dxs[x][2]
                     + tanhf(a4) * dxs[x][3];
            Hc[((size_t)bP * NX + x) * HID + o0 + ol] = hv;
            __syncthreads();
        }
        gbar();

        // ---- P2b: DFT + Av(bf16) + update, m-tile j*3, both batches ----
        {
            if (t < 768) {
                int h = t & 127, r2 = t >> 7;       // r2 0..5
                int bl = r2 & 1, ml = r2 >> 1;
                vsl[bl][ml][h] =
                    vcur[((size_t)(g * 2 + bl) * MODES + m0 + ml) * HID + h];
            }
            __syncthreads();
            int r = t >> 7;                         // 0..7
            if (r < 6) {
                int o = t & 127;
                int ml = r >> 1, bl = r & 1;
                int m = m0 + ml;
                int b = g * 2 + bl;
                // DFT over x: Hc coalesced, trig broadcast
                const float* hp = Hc + (size_t)b * NX * HID + o;
                const float2* trow = T2m + (size_t)m * NX;
                float fre = 0.f, fim = 0.f;
                #pragma unroll 4
                for (int x = 0; x < NX; ++x) {
                    float hv = hp[(size_t)x * HID];
                    float2 cs = trow[x];
                    fre += hv * cs.x;
                    fim -= hv * cs.y;
                }
                // Av over h: bf16 At2 coalesced (256B/wave), v broadcast
                const unsigned int* a2p = At2b + ((size_t)m * HID) * HID + o;
                float are = 0.f, aim = 0.f;
                #pragma unroll 4
                for (int h = 0; h < HID; ++h) {
                    unsigned int u = a2p[(size_t)h * HID];
                    float ax = __uint_as_float((u & 0xffffu) << 16);
                    float ay = __uint_as_float(u & 0xffff0000u);
                    float2 vv = vsl[bl][ml][h];
                    are += ax * vv.x - ay * vv.y;
                    aim += ay * vv.x - ax * vv.y;
                }
                float2 vo = vsl[bl][ml][o];
                vnxt[((size_t)b * MODES + m) * HID + o] =
                    make_float2(vo.x + are + fre, vo.y + aim + fim);
            }
            __syncthreads();
        }
        gbar();

        float2* tmp = vcur; vcur = vnxt; vnxt = tmp;
    }

    // ---- final flush: columns 48..63 ----
    {
        int xl = t >> 7, h = t & 127;
        int x = xg0 + xl;
        float vals[16];
        #pragma unroll
        for (int tt = 0; tt < 16; ++tt)
            vals[tt] = zbuf[(size_t)tt * ZSZ + ((size_t)bP * NX + x) * HID + h];
        float* dst = out + (((size_t)bP * HID + h) * NX + x) * NT + 48;
        #pragma unroll
        for (int q = 0; q < 4; ++q)
            ((float4*)dst)[q] = make_float4(vals[q*4], vals[q*4+1],
                                            vals[q*4+2], vals[q*4+3]);
    }
}

// ---------------------------------------------------------------------------
extern "C" void kernel_launch(void* const* d_in, const int* in_sizes, int n_in,
                              void* d_out, int out_size, void* d_ws, size_t ws_size,
                              hipStream_t stream) {
    const float* z0 = (const float*)d_in[0];
    const float* xi = (const float*)d_in[1];
    const float* A  = (const float*)d_in[2];
    const float* WF = (const float*)d_in[3];
    const float* WG = (const float*)d_in[4];
    float* out = (float*)d_out;

    float* ws = (float*)d_ws;
    size_t off = 0;
    auto alloc = [&](size_t n) { float* p = ws + off; off += n; return p; };

    float*  Ct   = alloc((size_t)MODES * NX);
    float*  St   = alloc((size_t)MODES * NX);
    float2* T2m  = (float2*)alloc((size_t)MODES * NX * 2);
    float4* Wt4  = (float4*)alloc((size_t)16 * HID * 8 * 4);
    float*  Wt1  = alloc((size_t)16 * HID * 8);
    unsigned int* At2b = (unsigned int*)alloc((size_t)MODES * HID * HID);
    float2* va   = (float2*)alloc((size_t)BATCH * MODES * HID * 2);
    float2* vb   = (float2*)alloc((size_t)BATCH * MODES * HID * 2);
    float*  Hcb  = alloc((size_t)BATCH * NX * HID);
    float*  dxib = alloc((size_t)(NT - 1) * BATCH * NX * NF);
    float*  zbuf = alloc(16 * ZSZ);
    int*    barc = (int*)alloc(NGRP * 64);

    hipMemsetAsync(barc, 0, NGRP * 64 * sizeof(int), stream);
    k_tables<<<MODES, 128, 0, stream>>>(Ct, St, T2m);
    {
        int total = (NT - 1) * BATCH * NX * NF;
        k_dxi<<<(total + 255) / 256, 256, 0, stream>>>(xi, dxib);
    }
    k_wt4<<<64, 256, 0, stream>>>(WF, WG, Wt4, Wt1);
    k_at2<<<dim3(4, 4, MODES), dim3(32, 8), 0, stream>>>(A, At2b);

    k_solve<<<NWG, TPB, 0, stream>>>(z0, Ct, St, T2m, Wt4, Wt1, At2b, dxib,
                                     va, vb, zbuf, Hcb, out, barc);
}